// Round 2
// baseline (290.656 us; speedup 1.0000x reference)
//
#include <hip/hip_runtime.h>
#include <cstdint>
#include <math.h>

#define B_ 64
#define S_ 512
#define H_ 1024
#define T_ 24
#define TP_ 32   // W padded to 32 rows (zeros) so B-fragment loads never go OOB
#define NC_ 8    // chunks per batch (parallel-scan)
#define CL_ 64   // chunk length in steps
#define CSTRIDE_ 600  // floats per (batch,chunk) record: 24x24 matrix + 24 log-scales

typedef unsigned int u32;
typedef unsigned short u16;
typedef __attribute__((ext_vector_type(8))) short short8v;  // 8 bf16 = 4 VGPRs
typedef __attribute__((ext_vector_type(4))) float f32x4;
typedef __attribute__((ext_vector_type(4))) u32 uint4v;

// readlane: value from lane `sl` (wave-uniform index ok), bitcast through uint
__device__ __forceinline__ float rl_f32(float x, int sl) {
    return __uint_as_float(__builtin_amdgcn_readlane(__float_as_uint(x), sl));
}

// Exact-ish two-term split: f = hi + lo (both bf16 by truncation).
// Packs two elements' hi (lo) into one u32, low element in low half.
__device__ __forceinline__ void split_pk(float f0, float f1, u32& hpk, u32& lpk) {
    const u32 u0 = __float_as_uint(f0), u1 = __float_as_uint(f1);
    const u32 t1 = u1 & 0xffff0000u;
    hpk = (u0 >> 16) | t1;
    const float fl0 = f0 - __uint_as_float(u0 & 0xffff0000u);
    const float fl1 = f1 - __uint_as_float(t1);
    lpk = (__float_as_uint(fl0) >> 16) | (__float_as_uint(fl1) & 0xffff0000u);
}

// ---------------------------------------------------------------------------
// Kernel 0: one-shot W split fp32 -> bf16 hi/lo (RTNE), padded to 32 rows.
// Also zeroes the loss accumulator out[0] (re-zeroed every graph replay).
// ---------------------------------------------------------------------------
__global__ __launch_bounds__(256) void wcvt_kernel(const float* __restrict__ W,
                                                   u16* __restrict__ Wh,
                                                   u16* __restrict__ Wl,
                                                   float* __restrict__ out) {
    const int i = blockIdx.x * 256 + threadIdx.x;       // 0 .. 32*1024-1
    if (i == 0) out[0] = 0.f;
    const int t = i >> 10;
    const float f = (t < T_) ? W[i] : 0.f;              // W is [24][1024]; i = t*1024+k
    const u32 u = __float_as_uint(f);
    const u32 rh = u + 0x7fffu + ((u >> 16) & 1u);      // RTNE
    const u16 hb = (u16)(rh >> 16);
    const float fh = __uint_as_float((u32)hb << 16);
    const float fl = f - fh;
    const u32 u2 = __float_as_uint(fl);
    const u32 rl2 = u2 + 0x7fffu + ((u2 >> 16) & 1u);
    Wh[i] = hb;
    Wl[i] = (u16)(rl2 >> 16);
}

// ---------------------------------------------------------------------------
// Kernel 1: emission GEMM via MFMA (bf16 hi/lo split) — unchanged from R1.
// ---------------------------------------------------------------------------
__global__ __launch_bounds__(256) void gemm_kernel(const float* __restrict__ feats,
                                                   const u16* __restrict__ Wh,
                                                   const u16* __restrict__ Wl,
                                                   const float* __restrict__ bias,
                                                   float* __restrict__ emission) {
    const int tid  = threadIdx.x;
    const int lane = tid & 63;
    const int wv   = tid >> 6;            // wave 0..3
    const int r16  = lane & 15;           // A-row in tile / output col
    const int g    = lane >> 4;           // 0..3 (k-group)
    const int mtile = blockIdx.x * 4 + wv;

    const float* ap  = feats + ((long)mtile * 16 + r16) * H_ + g * 8;
    const u16* bh0p = Wh + r16 * H_ + g * 8;           // Nfrag0: cols 0..15
    const u16* bl0p = Wl + r16 * H_ + g * 8;
    const u16* bh1p = Wh + (r16 + 16) * H_ + g * 8;    // Nfrag1: cols 16..31 (zero-padded)
    const u16* bl1p = Wl + (r16 + 16) * H_ + g * 8;

    f32x4 acc0 = {0.f, 0.f, 0.f, 0.f};
    f32x4 acc1 = {0.f, 0.f, 0.f, 0.f};

#pragma unroll 4
    for (int kk = 0; kk < H_ / 32; ++kk) {
        const int ko = kk * 32;
        const float4 a0 = *(const float4*)(ap + ko);
        const float4 a1 = *(const float4*)(ap + ko + 4);
        const short8v bh0 = *(const short8v*)(bh0p + ko);
        const short8v bl0 = *(const short8v*)(bl0p + ko);
        const short8v bh1 = *(const short8v*)(bh1p + ko);
        const short8v bl1 = *(const short8v*)(bl1p + ko);

        u32 h0, l0, h1, l1, h2, l2, h3, l3;
        split_pk(a0.x, a0.y, h0, l0);
        split_pk(a0.z, a0.w, h1, l1);
        split_pk(a1.x, a1.y, h2, l2);
        split_pk(a1.z, a1.w, h3, l3);
        const uint4v hv = {h0, h1, h2, h3};
        const uint4v lv = {l0, l1, l2, l3};
        const short8v ah = __builtin_bit_cast(short8v, hv);
        const short8v al = __builtin_bit_cast(short8v, lv);

        acc0 = __builtin_amdgcn_mfma_f32_16x16x32_bf16(al, bh0, acc0, 0, 0, 0);
        acc0 = __builtin_amdgcn_mfma_f32_16x16x32_bf16(ah, bl0, acc0, 0, 0, 0);
        acc0 = __builtin_amdgcn_mfma_f32_16x16x32_bf16(ah, bh0, acc0, 0, 0, 0);
        acc1 = __builtin_amdgcn_mfma_f32_16x16x32_bf16(al, bh1, acc1, 0, 0, 0);
        acc1 = __builtin_amdgcn_mfma_f32_16x16x32_bf16(ah, bl1, acc1, 0, 0, 0);
        acc1 = __builtin_amdgcn_mfma_f32_16x16x32_bf16(ah, bh1, acc1, 0, 0, 0);
    }

    // epilogue: C/D layout col=lane&15, row=4*(lane>>4)+reg
    const float b0 = bias[r16];
    const float b1 = (r16 + 16 < T_) ? bias[r16 + 16] : 0.f;
    float* op = emission + ((long)mtile * 16 + g * 4) * T_;
#pragma unroll
    for (int r = 0; r < 4; ++r) {
        op[r * T_ + r16] = acc0[r] + b0;
        if (r16 + 16 < T_) op[r * T_ + r16 + 16] = acc1[r] + b1;
    }
}

// ---------------------------------------------------------------------------
// Kernel 2: parallel-scan pass 1. The forward recurrence p_s = p_{s-1}·A_s,
// A_s[t,j] = E[t,j]·X_s[j] (identity for s>=len) is associative: each block-
// wave evolves 3 ROWS of the chunk-product matrix M_c = prod A_s over its
// 64-step chunk. grid = B*NC*8 waves (4096) -> 4 waves/SIMD over the whole
// chip, vs the old 64-wave serial scan. Rows are independent: per step,
// m_r[j] <- (sum_t m_r[t]·E[t,j])·X[j] via readlane broadcast.
// Renorm every 8 steps by wave-max of slot 0 (always >0: identity start).
// Per-row log-scales stored for pass 2.
// ---------------------------------------------------------------------------
#define DECL_E(i) const float E##i = __expf(trans[(i) * T_ + jj]);
#define FMA4M(mv, i0, i1, i2, i3)                                              \
    s0 = fmaf(rl_f32(mv, i0), E##i0, s0);                                      \
    s1 = fmaf(rl_f32(mv, i1), E##i1, s1);                                      \
    s2 = fmaf(rl_f32(mv, i2), E##i2, s2);                                      \
    s3 = fmaf(rl_f32(mv, i3), E##i3, s3);
#define UPDATE(mv)                                                             \
    {                                                                          \
        float s0 = 0.f, s1 = 0.f, s2 = 0.f, s3 = 0.f;                          \
        FMA4M(mv, 0, 1, 2, 3)                                                  \
        FMA4M(mv, 4, 5, 6, 7)                                                  \
        FMA4M(mv, 8, 9, 10, 11)                                                \
        FMA4M(mv, 12, 13, 14, 15)                                              \
        FMA4M(mv, 16, 17, 18, 19)                                              \
        FMA4M(mv, 20, 21, 22, 23)                                              \
        mv = ((s0 + s1) + (s2 + s3)) * X;                                      \
    }

__global__ __launch_bounds__(64, 1) void chunk_kernel(const float* __restrict__ emission,
                                                      const int* __restrict__ mask,
                                                      const float* __restrict__ trans,
                                                      float* __restrict__ wsM) {
    const int bid = blockIdx.x;
    const int w = bid & 7;               // row-group 0..7 (rows 3w..3w+2)
    const int c = (bid >> 3) & (NC_ - 1);
    const int b = bid >> 6;
    const int j = threadIdx.x;
    const int jj = j < 24 ? j : 23;      // lanes >=24 mirror j=23 (harmless)

    const float* em = emission + (long)b * S_ * T_;
    const int* mk = mask + b * S_;

    // len = sum(mask row) (prefix-contiguous by construction)
    int mc = 0;
#pragma unroll
    for (int k = 0; k < 8; ++k) mc += mk[j + k * 64];
#pragma unroll
    for (int off = 32; off; off >>= 1) mc += __shfl_xor(mc, off);
    const int len = __builtin_amdgcn_readfirstlane(mc);

    DECL_E(0)  DECL_E(1)  DECL_E(2)  DECL_E(3)  DECL_E(4)  DECL_E(5)
    DECL_E(6)  DECL_E(7)  DECL_E(8)  DECL_E(9)  DECL_E(10) DECL_E(11)
    DECL_E(12) DECL_E(13) DECL_E(14) DECL_E(15) DECL_E(16) DECL_E(17)
    DECL_E(18) DECL_E(19) DECL_E(20) DECL_E(21) DECL_E(22) DECL_E(23)

    const int lo = 1 + c * CL_;                 // first step of this chunk
    const int hi = min(lo + CL_, S_);           // one-past-last step
    const int send = min(hi, len);              // active end (uniform)
    const int r0 = 3 * w;

    // M rows start as identity rows
    float m0 = (jj == r0 + 0) ? 1.f : 0.f;
    float m1 = (jj == r0 + 1) ? 1.f : 0.f;
    float m2 = (jj == r0 + 2) ? 1.f : 0.f;
    float Cw = 0.f;

    // prefetch ring of RAW emissions, depth 8
    float lb[8];
#pragma unroll
    for (int k = 0; k < 8; ++k) lb[k] = em[(lo + k) * T_ + jj];

    for (int sb = lo; sb < hi; sb += 8) {
#pragma unroll
        for (int k = 0; k < 8; ++k) {
            const int s = sb + k;
            const float X = __expf(lb[k]);       // loaded 8 steps ago
            const int sp = s + 8;
            lb[k] = (sp < S_) ? em[sp * T_ + jj] : 0.f;
            if (s < send) {                      // uniform branch
                UPDATE(m0)
                UPDATE(m1)
                UPDATE(m2)
            }
        }
        // renorm every 8 steps: wave-max of slot 0 (>0 always)
        float r = m0;
#pragma unroll
        for (int off = 32; off; off >>= 1) r = fmaxf(r, __shfl_xor(r, off));
        const float inv = 1.0f / r;
        m0 *= inv;
        m1 *= inv;
        m2 *= inv;
        Cw += __logf(r);
    }

    float* outp = wsM + (long)(b * NC_ + c) * CSTRIDE_;
    if (j < 24) {
        outp[(r0 + 0) * 24 + j] = m0;
        outp[(r0 + 1) * 24 + j] = m1;
        outp[(r0 + 2) * 24 + j] = m2;
    }
    if (j == 0) {
        outp[576 + r0 + 0] = Cw;
        outp[576 + r0 + 1] = Cw;
        outp[576 + r0 + 2] = Cw;
    }
}

// ---------------------------------------------------------------------------
// Kernel 3: pass 2 — apply the 8 chunk matrices to p0, fold per-row scales,
// compute logZ; plus gold-path score; atomicAdd (logZ - score)/B into out[0].
// ---------------------------------------------------------------------------
__global__ __launch_bounds__(64) void finalize_kernel(const float* __restrict__ emission,
                                                      const int* __restrict__ target,
                                                      const int* __restrict__ mask,
                                                      const float* __restrict__ trans,
                                                      const float* __restrict__ wsM,
                                                      float* __restrict__ out) {
    const int b = blockIdx.x;
    const int j = threadIdx.x;
    const int jj = j < 24 ? j : 23;
    const float* em = emission + (long)b * S_ * T_;
    const int* mk = mask + b * S_;

    float p = (j < 24) ? __expf(em[j]) : 0.f;   // p0
    float C = 0.f;

    for (int c = 0; c < NC_; ++c) {
        const float* Mc = wsM + (long)(b * NC_ + c) * CSTRIDE_;
        // bring rows to a common scale: fold exp(Ls - Lmax) into p
        float Ls = (j < 24) ? Mc[576 + j] : -3.0e38f;
        float Lmax = Ls;
#pragma unroll
        for (int off = 32; off; off >>= 1) Lmax = fmaxf(Lmax, __shfl_xor(Lmax, off));
        p *= __expf(Ls - Lmax);                 // lanes>=24: p stays 0
        C += Lmax;
        // p_new[j] = sum_t p[t] * Mc[t][j]
        float s0 = 0.f, s1 = 0.f, s2 = 0.f, s3 = 0.f;
#pragma unroll
        for (int t = 0; t < 24; t += 4) {
            s0 = fmaf(rl_f32(p, t + 0), Mc[(t + 0) * 24 + jj], s0);
            s1 = fmaf(rl_f32(p, t + 1), Mc[(t + 1) * 24 + jj], s1);
            s2 = fmaf(rl_f32(p, t + 2), Mc[(t + 2) * 24 + jj], s2);
            s3 = fmaf(rl_f32(p, t + 3), Mc[(t + 3) * 24 + jj], s3);
        }
        p = (j < 24) ? ((s0 + s1) + (s2 + s3)) : 0.f;
        // renorm (p[0] > 0 always)
        const float r = rl_f32(p, 0);
        p *= (1.0f / r);
        C += __logf(r);
    }

    float ex = p;                               // lanes>=24 already 0
#pragma unroll
    for (int off = 32; off; off >>= 1) ex += __shfl_down(ex, off);

    // gold-path score (all 64 lanes)
    float ssum = 0.f;
#pragma unroll
    for (int kk = 0; kk < S_ / 64; ++kk) {
        const int s = j + kk * 64;
        if (mk[s]) {
            const int tg = target[b * S_ + s];
            float v = em[s * T_ + tg];
            if (s > 0) v += trans[target[b * S_ + s - 1] * T_ + tg];
            ssum += v;
        }
    }
#pragma unroll
    for (int off = 32; off; off >>= 1) ssum += __shfl_down(ssum, off);

    if (j == 0) {
        const float logZ = C + __logf(ex);
        atomicAdd(out, (logZ - ssum) * (1.0f / B_));
    }
}

extern "C" void kernel_launch(void* const* d_in, const int* in_sizes, int n_in,
                              void* d_out, int out_size, void* d_ws, size_t ws_size,
                              hipStream_t stream) {
    const float* feats  = (const float*)d_in[0];
    const int*   target = (const int*)d_in[1];
    const int*   mask   = (const int*)d_in[2];
    const float* W      = (const float*)d_in[3];
    const float* bias   = (const float*)d_in[4];
    const float* trans  = (const float*)d_in[5];

    float* out = (float*)d_out;
    float* emission = out + 1;            // output 1, written in place
    u16* Wh = (u16*)d_ws;                 // 32*1024 bf16 = 64 KB
    u16* Wl = Wh + TP_ * H_;              // 64 KB
    float* wsM = (float*)((char*)d_ws + 131072);  // B*NC*600 floats = 1.2 MB

    wcvt_kernel<<<(TP_ * H_) / 256, 256, 0, stream>>>(W, Wh, Wl, out);
    gemm_kernel<<<512, 256, 0, stream>>>(feats, Wh, Wl, bias, emission);
    chunk_kernel<<<B_ * NC_ * 8, 64, 0, stream>>>(emission, mask, trans, wsM);
    finalize_kernel<<<B_, 64, 0, stream>>>(emission, target, mask, trans, wsM, out);
}

// Round 3
// 260.049 us; speedup vs baseline: 1.1177x; 1.1177x over previous
//
#include <hip/hip_runtime.h>
#include <cstdint>
#include <math.h>

#define B_ 64
#define S_ 512
#define H_ 1024
#define T_ 24
#define TP_ 32     // W padded to 32 rows (zeros) so B-fragment loads never go OOB
#define NC_ 32     // chunks per batch (parallel-scan)
#define CL_ 16     // chunk length in steps
#define KST_ 1040  // floats per (batch,chunk) record: 32x32 K row-major + Ls + pad

typedef unsigned int u32;
typedef unsigned short u16;
typedef __attribute__((ext_vector_type(8))) short short8v;  // 8 bf16 = 4 VGPRs
typedef __attribute__((ext_vector_type(4))) float f32x4;
typedef __attribute__((ext_vector_type(4))) u32 uint4v;

// readlane: value from lane `sl` (wave-uniform index ok), bitcast through uint
__device__ __forceinline__ float rl_f32(float x, int sl) {
    return __uint_as_float(__builtin_amdgcn_readlane(__float_as_uint(x), sl));
}

// Exact-ish two-term split: f = hi + lo (both bf16 by truncation).
// Packs two elements' hi (lo) into one u32, low element in low half.
__device__ __forceinline__ void split_pk(float f0, float f1, u32& hpk, u32& lpk) {
    const u32 u0 = __float_as_uint(f0), u1 = __float_as_uint(f1);
    const u32 t1 = u1 & 0xffff0000u;
    hpk = (u0 >> 16) | t1;
    const float fl0 = f0 - __uint_as_float(u0 & 0xffff0000u);
    const float fl1 = f1 - __uint_as_float(t1);
    lpk = (__float_as_uint(fl0) >> 16) | (__float_as_uint(fl1) & 0xffff0000u);
}

// ---------------------------------------------------------------------------
// Kernel 0: one-shot W split fp32 -> bf16 hi/lo (RTNE), padded to 32 rows.
// Also zeroes the loss accumulator out[0] (re-zeroed every graph replay).
// ---------------------------------------------------------------------------
__global__ __launch_bounds__(256) void wcvt_kernel(const float* __restrict__ W,
                                                   u16* __restrict__ Wh,
                                                   u16* __restrict__ Wl,
                                                   float* __restrict__ out) {
    const int i = blockIdx.x * 256 + threadIdx.x;       // 0 .. 32*1024-1
    if (i == 0) out[0] = 0.f;
    const int t = i >> 10;
    const float f = (t < T_) ? W[i] : 0.f;              // W is [24][1024]; i = t*1024+k
    const u32 u = __float_as_uint(f);
    const u32 rh = u + 0x7fffu + ((u >> 16) & 1u);      // RTNE
    const u16 hb = (u16)(rh >> 16);
    const float fh = __uint_as_float((u32)hb << 16);
    const float fl = f - fh;
    const u32 u2 = __float_as_uint(fl);
    const u32 rl2 = u2 + 0x7fffu + ((u2 >> 16) & 1u);
    Wh[i] = hb;
    Wl[i] = (u16)(rl2 >> 16);
}

// ---------------------------------------------------------------------------
// Kernel 1: emission GEMM via MFMA (bf16 hi/lo split) — unchanged (passed 2x).
// Verified conventions for mfma_f32_16x16x32_bf16 (by this kernel passing):
//   A[m][k]: m=lane&15, k=(lane>>4)*8+e ; B[k][n]: n=lane&15, k=(lane>>4)*8+e
//   D[m][n]: n=lane&15, m=(lane>>4)*4+reg
// ---------------------------------------------------------------------------
__global__ __launch_bounds__(256) void gemm_kernel(const float* __restrict__ feats,
                                                   const u16* __restrict__ Wh,
                                                   const u16* __restrict__ Wl,
                                                   const float* __restrict__ bias,
                                                   float* __restrict__ emission) {
    const int tid  = threadIdx.x;
    const int lane = tid & 63;
    const int wv   = tid >> 6;            // wave 0..3
    const int r16  = lane & 15;           // A-row in tile / output col
    const int g    = lane >> 4;           // 0..3 (k-group)
    const int mtile = blockIdx.x * 4 + wv;

    const float* ap  = feats + ((long)mtile * 16 + r16) * H_ + g * 8;
    const u16* bh0p = Wh + r16 * H_ + g * 8;           // Nfrag0: cols 0..15
    const u16* bl0p = Wl + r16 * H_ + g * 8;
    const u16* bh1p = Wh + (r16 + 16) * H_ + g * 8;    // Nfrag1: cols 16..31 (zero-padded)
    const u16* bl1p = Wl + (r16 + 16) * H_ + g * 8;

    f32x4 acc0 = {0.f, 0.f, 0.f, 0.f};
    f32x4 acc1 = {0.f, 0.f, 0.f, 0.f};

#pragma unroll 4
    for (int kk = 0; kk < H_ / 32; ++kk) {
        const int ko = kk * 32;
        const float4 a0 = *(const float4*)(ap + ko);
        const float4 a1 = *(const float4*)(ap + ko + 4);
        const short8v bh0 = *(const short8v*)(bh0p + ko);
        const short8v bl0 = *(const short8v*)(bl0p + ko);
        const short8v bh1 = *(const short8v*)(bh1p + ko);
        const short8v bl1 = *(const short8v*)(bl1p + ko);

        u32 h0, l0, h1, l1, h2, l2, h3, l3;
        split_pk(a0.x, a0.y, h0, l0);
        split_pk(a0.z, a0.w, h1, l1);
        split_pk(a1.x, a1.y, h2, l2);
        split_pk(a1.z, a1.w, h3, l3);
        const uint4v hv = {h0, h1, h2, h3};
        const uint4v lv = {l0, l1, l2, l3};
        const short8v ah = __builtin_bit_cast(short8v, hv);
        const short8v al = __builtin_bit_cast(short8v, lv);

        acc0 = __builtin_amdgcn_mfma_f32_16x16x32_bf16(al, bh0, acc0, 0, 0, 0);
        acc0 = __builtin_amdgcn_mfma_f32_16x16x32_bf16(ah, bl0, acc0, 0, 0, 0);
        acc0 = __builtin_amdgcn_mfma_f32_16x16x32_bf16(ah, bh0, acc0, 0, 0, 0);
        acc1 = __builtin_amdgcn_mfma_f32_16x16x32_bf16(al, bh1, acc1, 0, 0, 0);
        acc1 = __builtin_amdgcn_mfma_f32_16x16x32_bf16(ah, bl1, acc1, 0, 0, 0);
        acc1 = __builtin_amdgcn_mfma_f32_16x16x32_bf16(ah, bh1, acc1, 0, 0, 0);
    }

    // epilogue: C/D layout col=lane&15, row=4*(lane>>4)+reg
    const float b0 = bias[r16];
    const float b1 = (r16 + 16 < T_) ? bias[r16 + 16] : 0.f;
    float* op = emission + ((long)mtile * 16 + g * 4) * T_;
#pragma unroll
    for (int r = 0; r < 4; ++r) {
        op[r * T_ + r16] = acc0[r] + b0;
        if (r16 + 16 < T_) op[r * T_ + r16 + 16] = acc1[r] + b1;
    }
}

// ---------------------------------------------------------------------------
// Kernel 2: parallel-scan pass 1, MFMA form.
// Column-vector recurrence: P_s = diagX_s * E^T * P_{s-1}, X_s[j]=exp(em[s][j]),
// E[t][j]=exp(trans[t][j]) (zero-padded to 32). Chunk operator:
//   K <- diagX_s * (E^T * K),  K init = I(32).
// MFMA: D_IJ = A_I * B_J, A = E^T (fixed, bf16 hi/lo), B = K (rebuilt per step).
// One wave per (b,chunk): grid = 64*32 = 2048 waves = 2/SIMD chip-wide.
// D->B row regrouping via small LDS bounce (stride-18 pad: <=2-way conflicts).
// Row scale X[row] via ds_bpermute. Renorm every 8 steps by exact 2^e factor.
// ---------------------------------------------------------------------------
__global__ __launch_bounds__(64, 1) void chunk_kernel(const float* __restrict__ emission,
                                                      const int* __restrict__ mask,
                                                      const float* __restrict__ trans,
                                                      float* __restrict__ wsK) {
    __shared__ u32 lds[2][2][16][18];   // [hl][J][rowpair][col(16)+pad]
    const int bid = blockIdx.x;
    const int c_ = bid & (NC_ - 1);     // chunk
    const int b  = bid >> 5;
    const int l  = threadIdx.x;
    const int cc = l & 15;              // col-in-tile
    const int q  = l >> 4;              // lane quarter
    const int aq4 = (l & 48);           // 4*(4q) bytes, bpermute base

    const float* em = emission + (long)b * S_ * T_;
    const int* mk = mask + b * S_;

    // len = sum(mask row) (prefix-contiguous by construction)
    int mc = 0;
#pragma unroll
    for (int k = 0; k < 8; ++k) mc += mk[l + k * 64];
#pragma unroll
    for (int off = 32; off; off >>= 1) mc += __shfl_xor(mc, off);
    const int len = __builtin_amdgcn_readfirstlane(mc);

    const int lo = 1 + c_ * CL_;
    const int hi = min(lo + CL_, S_);
    const int send = min(hi, len);      // uniform

    // A-frags: A_I[m][k] = E^T[16I+cc][8q+e] = exp(trans[(8q+e)*24 + 16I+cc])
    short8v Ah[2], Al[2];
#pragma unroll
    for (int I = 0; I < 2; ++I) {
        const int j = 16 * I + cc;
        u32 hw[4], lw[4];
#pragma unroll
        for (int w = 0; w < 4; ++w) {
            const int t0 = 8 * q + 2 * w;
            const float v0 = (t0 < 24 && j < 24) ? __expf(trans[t0 * T_ + j]) : 0.f;
            const float v1 = (t0 + 1 < 24 && j < 24) ? __expf(trans[(t0 + 1) * T_ + j]) : 0.f;
            split_pk(v0, v1, hw[w], lw[w]);
        }
        const uint4v hv = {hw[0], hw[1], hw[2], hw[3]};
        const uint4v lv = {lw[0], lw[1], lw[2], lw[3]};
        Ah[I] = __builtin_bit_cast(short8v, hv);
        Al[I] = __builtin_bit_cast(short8v, lv);
    }

    // K regs (C/D layout): K[I][J] reg r holds K[16I+4q+r][16J+cc]; init identity
    f32x4 K[2][2];
#pragma unroll
    for (int I = 0; I < 2; ++I)
#pragma unroll
        for (int J = 0; J < 2; ++J)
#pragma unroll
            for (int r = 0; r < 4; ++r)
                K[I][J][r] = (16 * I + 4 * q + r == 16 * J + cc) ? 1.f : 0.f;

    // initial B words (identity): word w covers k = 8q+2w, 8q+2w+1; col 16J+cc
    u32 bh[2][4], bl[2][4];
#pragma unroll
    for (int J = 0; J < 2; ++J)
#pragma unroll
        for (int w = 0; w < 4; ++w) {
            const int k0 = 8 * q + 2 * w, col = 16 * J + cc;
            bh[J][w] = (k0 == col ? 0x3f80u : 0u) | (k0 + 1 == col ? 0x3f800000u : 0u);
            bl[J][w] = 0u;
        }

    // preload raw emissions for X: lane holds em[s][l&31] (clamped index)
    const int xj = ((l & 31) < 24) ? (l & 31) : 0;
    float xr_[CL_];
#pragma unroll
    for (int k = 0; k < CL_; ++k) {
        const int s = lo + k;
        xr_[k] = em[((s < S_) ? s : 0) * T_ + xj];
    }

    float Ls = 0.f;
    const f32x4 z4 = {0.f, 0.f, 0.f, 0.f};

#pragma unroll
    for (int k = 0; k < CL_; ++k) {
        const int s = lo + k;
        if (s < send) {                 // uniform branch
            const uint4v bh0v = {bh[0][0], bh[0][1], bh[0][2], bh[0][3]};
            const uint4v bh1v = {bh[1][0], bh[1][1], bh[1][2], bh[1][3]};
            const uint4v bl0v = {bl[0][0], bl[0][1], bl[0][2], bl[0][3]};
            const uint4v bl1v = {bl[1][0], bl[1][1], bl[1][2], bl[1][3]};
            const short8v B0h = __builtin_bit_cast(short8v, bh0v);
            const short8v B1h = __builtin_bit_cast(short8v, bh1v);
            const short8v B0l = __builtin_bit_cast(short8v, bl0v);
            const short8v B1l = __builtin_bit_cast(short8v, bl1v);

            f32x4 acc[2][2];
#pragma unroll
            for (int I = 0; I < 2; ++I) {
                acc[I][0] = __builtin_amdgcn_mfma_f32_16x16x32_bf16(Ah[I], B0h, z4, 0, 0, 0);
                acc[I][0] = __builtin_amdgcn_mfma_f32_16x16x32_bf16(Ah[I], B0l, acc[I][0], 0, 0, 0);
                acc[I][0] = __builtin_amdgcn_mfma_f32_16x16x32_bf16(Al[I], B0h, acc[I][0], 0, 0, 0);
                acc[I][1] = __builtin_amdgcn_mfma_f32_16x16x32_bf16(Ah[I], B1h, z4, 0, 0, 0);
                acc[I][1] = __builtin_amdgcn_mfma_f32_16x16x32_bf16(Ah[I], B1l, acc[I][1], 0, 0, 0);
                acc[I][1] = __builtin_amdgcn_mfma_f32_16x16x32_bf16(Al[I], B1h, acc[I][1], 0, 0, 0);
            }

            // row scales: X[16I+4q+r] via bpermute of lane-held X[l&31]
            const float X = __expf(xr_[k]);
            const int xi = __float_as_int(X);
            float xr0[4], xr1[4];
#pragma unroll
            for (int r = 0; r < 4; ++r) {
                xr0[r] = __int_as_float(__builtin_amdgcn_ds_bpermute(aq4 + 4 * r, xi));
                xr1[r] = __int_as_float(__builtin_amdgcn_ds_bpermute(aq4 + 64 + 4 * r, xi));
            }
#pragma unroll
            for (int J = 0; J < 2; ++J)
#pragma unroll
                for (int r = 0; r < 4; ++r) {
                    K[0][J][r] = acc[0][J][r] * xr0[r];
                    K[1][J][r] = acc[1][J][r] * xr1[r];
                }

            if (k == 7 || k == CL_ - 1) {   // exact power-of-2 renorm
                float mx = K[0][0][0];
#pragma unroll
                for (int I = 0; I < 2; ++I)
#pragma unroll
                    for (int J = 0; J < 2; ++J)
#pragma unroll
                        for (int r = 0; r < 4; ++r) mx = fmaxf(mx, K[I][J][r]);
#pragma unroll
                for (int off = 32; off; off >>= 1) mx = fmaxf(mx, __shfl_xor(mx, off));
                const u32 ef = __float_as_uint(mx) & 0x7f800000u;
                const float inv = __uint_as_float(0x7f000000u - ef);
#pragma unroll
                for (int I = 0; I < 2; ++I)
#pragma unroll
                    for (int J = 0; J < 2; ++J)
#pragma unroll
                        for (int r = 0; r < 4; ++r) K[I][J][r] *= inv;
                Ls += (float)((int)(ef >> 23) - 127) * 0.6931471805599453f;
            }

            if (k < CL_ - 1) {
                // pack K to bf16 hi/lo pairs and bounce through LDS to B layout
#pragma unroll
                for (int I = 0; I < 2; ++I)
#pragma unroll
                    for (int J = 0; J < 2; ++J)
#pragma unroll
                        for (int m = 0; m < 2; ++m) {
                            u32 h, lo_w;
                            split_pk(K[I][J][2 * m], K[I][J][2 * m + 1], h, lo_w);
                            const int p = 8 * I + 2 * q + m;
                            lds[0][J][p][cc] = h;
                            lds[1][J][p][cc] = lo_w;
                        }
                // single wave per block: DS-pipe in-order + compiler lgkmcnt
#pragma unroll
                for (int J = 0; J < 2; ++J)
#pragma unroll
                    for (int w = 0; w < 4; ++w) {
                        bh[J][w] = lds[0][J][4 * q + w][cc];
                        bl[J][w] = lds[1][J][4 * q + w][cc];
                    }
            }
        }
    }

    // store K row-major [j][t] (+ Ls) for pass 2
    float* outp = wsK + (long)(b * NC_ + c_) * KST_;
#pragma unroll
    for (int I = 0; I < 2; ++I)
#pragma unroll
        for (int J = 0; J < 2; ++J)
#pragma unroll
            for (int r = 0; r < 4; ++r)
                outp[(16 * I + 4 * q + r) * 32 + 16 * J + cc] = K[I][J][r];
    if (l == 0) outp[1024] = Ls;
}

// ---------------------------------------------------------------------------
// Kernel 3: pass 2 — p <- K_c * p over 32 chunks, fold scales, logZ;
// plus gold-path score; atomicAdd (logZ - score)/B into out[0].
// ---------------------------------------------------------------------------
#define ACC4(kv, t0)                                                           \
    s0 = fmaf(rl_f32(p, (t0) + 0), kv.x, s0);                                  \
    s1 = fmaf(rl_f32(p, (t0) + 1), kv.y, s1);                                  \
    s2 = fmaf(rl_f32(p, (t0) + 2), kv.z, s2);                                  \
    s3 = fmaf(rl_f32(p, (t0) + 3), kv.w, s3);

__global__ __launch_bounds__(64) void finalize_kernel(const float* __restrict__ emission,
                                                      const int* __restrict__ target,
                                                      const int* __restrict__ mask,
                                                      const float* __restrict__ trans,
                                                      const float* __restrict__ wsK,
                                                      float* __restrict__ out) {
    const int b = blockIdx.x;
    const int j = threadIdx.x;
    const int jj = j < 24 ? j : 23;
    const float* em = emission + (long)b * S_ * T_;
    const int* mk = mask + b * S_;

    float p = (j < 24) ? __expf(em[j]) : 0.f;   // p0
    float C = 0.f;

    for (int c = 0; c < NC_; ++c) {
        const float* base = wsK + (long)(b * NC_ + c) * KST_;
        C += base[1024];                        // chunk log-scale (uniform)
        const float4* rp = (const float4*)(base + jj * 32);
        const float4 k0 = rp[0], k1 = rp[1], k2 = rp[2], k3 = rp[3], k4 = rp[4], k5 = rp[5];
        float s0 = 0.f, s1 = 0.f, s2 = 0.f, s3 = 0.f;
        ACC4(k0, 0) ACC4(k1, 4) ACC4(k2, 8) ACC4(k3, 12) ACC4(k4, 16) ACC4(k5, 20)
        p = (j < 24) ? ((s0 + s1) + (s2 + s3)) : 0.f;
        // exact power-of-2 renorm by wave max
        float mx = p;
#pragma unroll
        for (int off = 32; off; off >>= 1) mx = fmaxf(mx, __shfl_xor(mx, off));
        const u32 ef = __float_as_uint(mx) & 0x7f800000u;
        p *= __uint_as_float(0x7f000000u - ef);
        C += (float)((int)(ef >> 23) - 127) * 0.6931471805599453f;
    }

    float ex = p;                               // lanes>=24 already 0
#pragma unroll
    for (int off = 32; off; off >>= 1) ex += __shfl_down(ex, off);

    // gold-path score (all 64 lanes)
    float ssum = 0.f;
#pragma unroll
    for (int kk = 0; kk < S_ / 64; ++kk) {
        const int s = j + kk * 64;
        if (mk[s]) {
            const int tg = target[b * S_ + s];
            float v = em[s * T_ + tg];
            if (s > 0) v += trans[target[b * S_ + s - 1] * T_ + tg];
            ssum += v;
        }
    }
#pragma unroll
    for (int off = 32; off; off >>= 1) ssum += __shfl_down(ssum, off);

    if (j == 0) {
        const float logZ = C + __logf(ex);
        atomicAdd(out, (logZ - ssum) * (1.0f / B_));
    }
}

extern "C" void kernel_launch(void* const* d_in, const int* in_sizes, int n_in,
                              void* d_out, int out_size, void* d_ws, size_t ws_size,
                              hipStream_t stream) {
    const float* feats  = (const float*)d_in[0];
    const int*   target = (const int*)d_in[1];
    const int*   mask   = (const int*)d_in[2];
    const float* W      = (const float*)d_in[3];
    const float* bias   = (const float*)d_in[4];
    const float* trans  = (const float*)d_in[5];

    float* out = (float*)d_out;
    float* emission = out + 1;            // output 1, written in place
    u16* Wh = (u16*)d_ws;                 // 32*1024 bf16 = 64 KB
    u16* Wl = Wh + TP_ * H_;              // 64 KB
    float* wsK = (float*)((char*)d_ws + 131072);  // 2048 * 1040 floats ~ 8.5 MB

    wcvt_kernel<<<(TP_ * H_) / 256, 256, 0, stream>>>(W, Wh, Wl, out);
    gemm_kernel<<<512, 256, 0, stream>>>(feats, Wh, Wl, bias, emission);
    chunk_kernel<<<B_ * NC_, 64, 0, stream>>>(emission, mask, trans, wsK);
    finalize_kernel<<<B_, 64, 0, stream>>>(emission, target, mask, trans, wsK, out);
}

// Round 4
// 258.974 us; speedup vs baseline: 1.1223x; 1.0041x over previous
//
#include <hip/hip_runtime.h>
#include <cstdint>
#include <math.h>

#define B_ 64
#define S_ 512
#define H_ 1024
#define T_ 24
#define TP_ 32     // W padded to 32 rows (zeros) so B-fragment loads never go OOB
#define NC_ 32     // chunks per batch (parallel-scan)
#define CL_ 16     // chunk length in steps
#define KST_ 1040  // floats per (batch,chunk) record: 32x32 K row-major + Ls + pad

typedef unsigned int u32;
typedef unsigned short u16;
typedef __attribute__((ext_vector_type(8))) short short8v;  // 8 bf16 = 4 VGPRs
typedef __attribute__((ext_vector_type(4))) float f32x4;
typedef __attribute__((ext_vector_type(4))) u32 uint4v;

// readlane: value from lane `sl` (wave-uniform index ok), bitcast through uint
__device__ __forceinline__ float rl_f32(float x, int sl) {
    return __uint_as_float(__builtin_amdgcn_readlane(__float_as_uint(x), sl));
}

// Exact-ish two-term split: f = hi + lo (both bf16 by truncation).
// Packs two elements' hi (lo) into one u32, low element in low half.
__device__ __forceinline__ void split_pk(float f0, float f1, u32& hpk, u32& lpk) {
    const u32 u0 = __float_as_uint(f0), u1 = __float_as_uint(f1);
    const u32 t1 = u1 & 0xffff0000u;
    hpk = (u0 >> 16) | t1;
    const float fl0 = f0 - __uint_as_float(u0 & 0xffff0000u);
    const float fl1 = f1 - __uint_as_float(t1);
    lpk = (__float_as_uint(fl0) >> 16) | (__float_as_uint(fl1) & 0xffff0000u);
}

// ---------------------------------------------------------------------------
// Kernel 0: one-shot W split fp32 -> bf16 hi/lo (RTNE), padded to 32 rows.
// Also zeroes the loss accumulator out[0] (re-zeroed every graph replay).
// ---------------------------------------------------------------------------
__global__ __launch_bounds__(256) void wcvt_kernel(const float* __restrict__ W,
                                                   u16* __restrict__ Wh,
                                                   u16* __restrict__ Wl,
                                                   float* __restrict__ out) {
    const int i = blockIdx.x * 256 + threadIdx.x;       // 0 .. 32*1024-1
    if (i == 0) out[0] = 0.f;
    const int t = i >> 10;
    const float f = (t < T_) ? W[i] : 0.f;              // W is [24][1024]; i = t*1024+k
    const u32 u = __float_as_uint(f);
    const u32 rh = u + 0x7fffu + ((u >> 16) & 1u);      // RTNE
    const u16 hb = (u16)(rh >> 16);
    const float fh = __uint_as_float((u32)hb << 16);
    const float fl = f - fh;
    const u32 u2 = __float_as_uint(fl);
    const u32 rl2 = u2 + 0x7fffu + ((u2 >> 16) & 1u);
    Wh[i] = hb;
    Wl[i] = (u16)(rl2 >> 16);
}

// ---------------------------------------------------------------------------
// Kernel 1: emission GEMM via MFMA (bf16 hi/lo split).
// R4: 2-way K-split for occupancy. Wave = one 16-row M-tile x 32 cols x HALF
// of K (512). Grid 1024 blocks x 4 waves = 4096 waves = 4/SIMD chip-wide
// (was 2/SIMD) -> 2x outstanding loads, BW-saturating. Partner waves (same
// M-tile, other K-half) combine partials through a 4KB LDS bounce.
// Explicit 3-stage software-pipelined loads keep VGPR ~115 (<128 so
// __launch_bounds__(256,4) occupancy materializes).
// Verified conventions for mfma_f32_16x16x32_bf16 (by this kernel passing):
//   A[m][k]: m=lane&15, k=(lane>>4)*8+e ; B[k][n]: n=lane&15, k=(lane>>4)*8+e
//   D[m][n]: n=lane&15, m=(lane>>4)*4+reg
// ---------------------------------------------------------------------------
__global__ __launch_bounds__(256, 4) void gemm_kernel(const float* __restrict__ feats,
                                                      const u16* __restrict__ Wh,
                                                      const u16* __restrict__ Wl,
                                                      const float* __restrict__ bias,
                                                      float* __restrict__ emission) {
    __shared__ f32x4 ldsP[2][64][2];      // partner partials [mtile-in-block][lane][acc0/1]
    const int tid  = threadIdx.x;
    const int lane = tid & 63;
    const int wv   = tid >> 6;            // wave 0..3
    const int mt_in = wv & 1;             // which M-tile of this block
    const int kh    = wv >> 1;            // K-half 0/1
    const int r16  = lane & 15;           // A-row in tile / output col
    const int g    = lane >> 4;           // 0..3 (k-group)
    const int mtile = blockIdx.x * 2 + mt_in;

    const long ko0 = (long)kh * 512 + g * 8;
    const float* ap  = feats + ((long)mtile * 16 + r16) * H_ + ko0;
    const u16* bh0p = Wh + r16 * H_ + ko0;           // Nfrag0: cols 0..15
    const u16* bl0p = Wl + r16 * H_ + ko0;
    const u16* bh1p = Wh + (r16 + 16) * H_ + ko0;    // Nfrag1: cols 16..31 (zero-padded)
    const u16* bl1p = Wl + (r16 + 16) * H_ + ko0;

    f32x4 acc0 = {0.f, 0.f, 0.f, 0.f};
    f32x4 acc1 = {0.f, 0.f, 0.f, 0.f};

    // 3-stage software pipeline (all indices compile-time under full unroll)
    float4 A0[3], A1[3];
    short8v BH0[3], BL0[3], BH1[3], BL1[3];
#pragma unroll
    for (int p = 0; p < 3; ++p) {
        const int ko = p * 32;
        A0[p]  = *(const float4*)(ap + ko);
        A1[p]  = *(const float4*)(ap + ko + 4);
        BH0[p] = *(const short8v*)(bh0p + ko);
        BL0[p] = *(const short8v*)(bl0p + ko);
        BH1[p] = *(const short8v*)(bh1p + ko);
        BL1[p] = *(const short8v*)(bl1p + ko);
    }

#pragma unroll
    for (int kk = 0; kk < 16; ++kk) {
        const int sl = kk % 3;
        const float4 a0 = A0[sl];
        const float4 a1 = A1[sl];
        const short8v bh0 = BH0[sl];
        const short8v bl0 = BL0[sl];
        const short8v bh1 = BH1[sl];
        const short8v bl1 = BL1[sl];
        if (kk + 3 < 16) {                 // refill freed slot, 3 iters ahead
            const int ko = (kk + 3) * 32;
            A0[sl]  = *(const float4*)(ap + ko);
            A1[sl]  = *(const float4*)(ap + ko + 4);
            BH0[sl] = *(const short8v*)(bh0p + ko);
            BL0[sl] = *(const short8v*)(bl0p + ko);
            BH1[sl] = *(const short8v*)(bh1p + ko);
            BL1[sl] = *(const short8v*)(bl1p + ko);
        }

        u32 h0, l0, h1, l1, h2, l2, h3, l3;
        split_pk(a0.x, a0.y, h0, l0);
        split_pk(a0.z, a0.w, h1, l1);
        split_pk(a1.x, a1.y, h2, l2);
        split_pk(a1.z, a1.w, h3, l3);
        const uint4v hv = {h0, h1, h2, h3};
        const uint4v lv = {l0, l1, l2, l3};
        const short8v ah = __builtin_bit_cast(short8v, hv);
        const short8v al = __builtin_bit_cast(short8v, lv);

        acc0 = __builtin_amdgcn_mfma_f32_16x16x32_bf16(al, bh0, acc0, 0, 0, 0);
        acc0 = __builtin_amdgcn_mfma_f32_16x16x32_bf16(ah, bl0, acc0, 0, 0, 0);
        acc0 = __builtin_amdgcn_mfma_f32_16x16x32_bf16(ah, bh0, acc0, 0, 0, 0);
        acc1 = __builtin_amdgcn_mfma_f32_16x16x32_bf16(al, bh1, acc1, 0, 0, 0);
        acc1 = __builtin_amdgcn_mfma_f32_16x16x32_bf16(ah, bl1, acc1, 0, 0, 0);
        acc1 = __builtin_amdgcn_mfma_f32_16x16x32_bf16(ah, bh1, acc1, 0, 0, 0);
    }

    // combine K-halves: kh=1 waves publish, kh=0 waves reduce + write out
    if (kh == 1) {
        ldsP[mt_in][lane][0] = acc0;
        ldsP[mt_in][lane][1] = acc1;
    }
    __syncthreads();
    if (kh == 0) {
        const f32x4 p0 = ldsP[mt_in][lane][0];
        const f32x4 p1 = ldsP[mt_in][lane][1];
#pragma unroll
        for (int r = 0; r < 4; ++r) {
            acc0[r] += p0[r];
            acc1[r] += p1[r];
        }
        // epilogue: C/D layout col=lane&15, row=4*(lane>>4)+reg
        const float b0 = bias[r16];
        const float b1 = (r16 + 16 < T_) ? bias[r16 + 16] : 0.f;
        float* op = emission + ((long)mtile * 16 + g * 4) * T_;
#pragma unroll
        for (int r = 0; r < 4; ++r) {
            op[r * T_ + r16] = acc0[r] + b0;
            if (r16 + 16 < T_) op[r * T_ + r16 + 16] = acc1[r] + b1;
        }
    }
}

// ---------------------------------------------------------------------------
// Kernel 2: parallel-scan pass 1, MFMA form — unchanged from R3 (passed).
// Column-vector recurrence: P_s = diagX_s * E^T * P_{s-1}, X_s[j]=exp(em[s][j]),
// E[t][j]=exp(trans[t][j]) (zero-padded to 32). Chunk operator:
//   K <- diagX_s * (E^T * K),  K init = I(32).
// ---------------------------------------------------------------------------
__global__ __launch_bounds__(64, 1) void chunk_kernel(const float* __restrict__ emission,
                                                      const int* __restrict__ mask,
                                                      const float* __restrict__ trans,
                                                      float* __restrict__ wsK) {
    __shared__ u32 lds[2][2][16][18];   // [hl][J][rowpair][col(16)+pad]
    const int bid = blockIdx.x;
    const int c_ = bid & (NC_ - 1);     // chunk
    const int b  = bid >> 5;
    const int l  = threadIdx.x;
    const int cc = l & 15;              // col-in-tile
    const int q  = l >> 4;              // lane quarter
    const int aq4 = (l & 48);           // 4*(4q) bytes, bpermute base

    const float* em = emission + (long)b * S_ * T_;
    const int* mk = mask + b * S_;

    // len = sum(mask row) (prefix-contiguous by construction)
    int mc = 0;
#pragma unroll
    for (int k = 0; k < 8; ++k) mc += mk[l + k * 64];
#pragma unroll
    for (int off = 32; off; off >>= 1) mc += __shfl_xor(mc, off);
    const int len = __builtin_amdgcn_readfirstlane(mc);

    const int lo = 1 + c_ * CL_;
    const int hi = min(lo + CL_, S_);
    const int send = min(hi, len);      // uniform

    // A-frags: A_I[m][k] = E^T[16I+cc][8q+e] = exp(trans[(8q+e)*24 + 16I+cc])
    short8v Ah[2], Al[2];
#pragma unroll
    for (int I = 0; I < 2; ++I) {
        const int j = 16 * I + cc;
        u32 hw[4], lw[4];
#pragma unroll
        for (int w = 0; w < 4; ++w) {
            const int t0 = 8 * q + 2 * w;
            const float v0 = (t0 < 24 && j < 24) ? __expf(trans[t0 * T_ + j]) : 0.f;
            const float v1 = (t0 + 1 < 24 && j < 24) ? __expf(trans[(t0 + 1) * T_ + j]) : 0.f;
            split_pk(v0, v1, hw[w], lw[w]);
        }
        const uint4v hv = {hw[0], hw[1], hw[2], hw[3]};
        const uint4v lv = {lw[0], lw[1], lw[2], lw[3]};
        Ah[I] = __builtin_bit_cast(short8v, hv);
        Al[I] = __builtin_bit_cast(short8v, lv);
    }

    // K regs (C/D layout): K[I][J] reg r holds K[16I+4q+r][16J+cc]; init identity
    f32x4 K[2][2];
#pragma unroll
    for (int I = 0; I < 2; ++I)
#pragma unroll
        for (int J = 0; J < 2; ++J)
#pragma unroll
            for (int r = 0; r < 4; ++r)
                K[I][J][r] = (16 * I + 4 * q + r == 16 * J + cc) ? 1.f : 0.f;

    // initial B words (identity): word w covers k = 8q+2w, 8q+2w+1; col 16J+cc
    u32 bh[2][4], bl[2][4];
#pragma unroll
    for (int J = 0; J < 2; ++J)
#pragma unroll
        for (int w = 0; w < 4; ++w) {
            const int k0 = 8 * q + 2 * w, col = 16 * J + cc;
            bh[J][w] = (k0 == col ? 0x3f80u : 0u) | (k0 + 1 == col ? 0x3f800000u : 0u);
            bl[J][w] = 0u;
        }

    // preload raw emissions for X: lane holds em[s][l&31] (clamped index)
    const int xj = ((l & 31) < 24) ? (l & 31) : 0;
    float xr_[CL_];
#pragma unroll
    for (int k = 0; k < CL_; ++k) {
        const int s = lo + k;
        xr_[k] = em[((s < S_) ? s : 0) * T_ + xj];
    }

    float Ls = 0.f;
    const f32x4 z4 = {0.f, 0.f, 0.f, 0.f};

#pragma unroll
    for (int k = 0; k < CL_; ++k) {
        const int s = lo + k;
        if (s < send) {                 // uniform branch
            const uint4v bh0v = {bh[0][0], bh[0][1], bh[0][2], bh[0][3]};
            const uint4v bh1v = {bh[1][0], bh[1][1], bh[1][2], bh[1][3]};
            const uint4v bl0v = {bl[0][0], bl[0][1], bl[0][2], bl[0][3]};
            const uint4v bl1v = {bl[1][0], bl[1][1], bl[1][2], bl[1][3]};
            const short8v B0h = __builtin_bit_cast(short8v, bh0v);
            const short8v B1h = __builtin_bit_cast(short8v, bh1v);
            const short8v B0l = __builtin_bit_cast(short8v, bl0v);
            const short8v B1l = __builtin_bit_cast(short8v, bl1v);

            f32x4 acc[2][2];
#pragma unroll
            for (int I = 0; I < 2; ++I) {
                acc[I][0] = __builtin_amdgcn_mfma_f32_16x16x32_bf16(Ah[I], B0h, z4, 0, 0, 0);
                acc[I][0] = __builtin_amdgcn_mfma_f32_16x16x32_bf16(Ah[I], B0l, acc[I][0], 0, 0, 0);
                acc[I][0] = __builtin_amdgcn_mfma_f32_16x16x32_bf16(Al[I], B0h, acc[I][0], 0, 0, 0);
                acc[I][1] = __builtin_amdgcn_mfma_f32_16x16x32_bf16(Ah[I], B1h, z4, 0, 0, 0);
                acc[I][1] = __builtin_amdgcn_mfma_f32_16x16x32_bf16(Ah[I], B1l, acc[I][1], 0, 0, 0);
                acc[I][1] = __builtin_amdgcn_mfma_f32_16x16x32_bf16(Al[I], B1h, acc[I][1], 0, 0, 0);
            }

            // row scales: X[16I+4q+r] via bpermute of lane-held X[l&31]
            const float X = __expf(xr_[k]);
            const int xi = __float_as_int(X);
            float xr0[4], xr1[4];
#pragma unroll
            for (int r = 0; r < 4; ++r) {
                xr0[r] = __int_as_float(__builtin_amdgcn_ds_bpermute(aq4 + 4 * r, xi));
                xr1[r] = __int_as_float(__builtin_amdgcn_ds_bpermute(aq4 + 64 + 4 * r, xi));
            }
#pragma unroll
            for (int J = 0; J < 2; ++J)
#pragma unroll
                for (int r = 0; r < 4; ++r) {
                    K[0][J][r] = acc[0][J][r] * xr0[r];
                    K[1][J][r] = acc[1][J][r] * xr1[r];
                }

            if (k == 7 || k == CL_ - 1) {   // exact power-of-2 renorm
                float mx = K[0][0][0];
#pragma unroll
                for (int I = 0; I < 2; ++I)
#pragma unroll
                    for (int J = 0; J < 2; ++J)
#pragma unroll
                        for (int r = 0; r < 4; ++r) mx = fmaxf(mx, K[I][J][r]);
#pragma unroll
                for (int off = 32; off; off >>= 1) mx = fmaxf(mx, __shfl_xor(mx, off));
                const u32 ef = __float_as_uint(mx) & 0x7f800000u;
                const float inv = __uint_as_float(0x7f000000u - ef);
#pragma unroll
                for (int I = 0; I < 2; ++I)
#pragma unroll
                    for (int J = 0; J < 2; ++J)
#pragma unroll
                        for (int r = 0; r < 4; ++r) K[I][J][r] *= inv;
                Ls += (float)((int)(ef >> 23) - 127) * 0.6931471805599453f;
            }

            if (k < CL_ - 1) {
                // pack K to bf16 hi/lo pairs and bounce through LDS to B layout
#pragma unroll
                for (int I = 0; I < 2; ++I)
#pragma unroll
                    for (int J = 0; J < 2; ++J)
#pragma unroll
                        for (int m = 0; m < 2; ++m) {
                            u32 h, lo_w;
                            split_pk(K[I][J][2 * m], K[I][J][2 * m + 1], h, lo_w);
                            const int p = 8 * I + 2 * q + m;
                            lds[0][J][p][cc] = h;
                            lds[1][J][p][cc] = lo_w;
                        }
                // single wave per block: DS-pipe in-order + compiler lgkmcnt
#pragma unroll
                for (int J = 0; J < 2; ++J)
#pragma unroll
                    for (int w = 0; w < 4; ++w) {
                        bh[J][w] = lds[0][J][4 * q + w][cc];
                        bl[J][w] = lds[1][J][4 * q + w][cc];
                    }
            }
        }
    }

    // store K row-major [j][t] (+ Ls) for pass 2
    float* outp = wsK + (long)(b * NC_ + c_) * KST_;
#pragma unroll
    for (int I = 0; I < 2; ++I)
#pragma unroll
        for (int J = 0; J < 2; ++J)
#pragma unroll
            for (int r = 0; r < 4; ++r)
                outp[(16 * I + 4 * q + r) * 32 + 16 * J + cc] = K[I][J][r];
    if (l == 0) outp[1024] = Ls;
}

// ---------------------------------------------------------------------------
// Kernel 3: pass 2 — p <- K_c * p over 32 chunks, fold scales, logZ;
// plus gold-path score; atomicAdd (logZ - score)/B into out[0].
// ---------------------------------------------------------------------------
#define ACC4(kv, t0)                                                           \
    s0 = fmaf(rl_f32(p, (t0) + 0), kv.x, s0);                                  \
    s1 = fmaf(rl_f32(p, (t0) + 1), kv.y, s1);                                  \
    s2 = fmaf(rl_f32(p, (t0) + 2), kv.z, s2);                                  \
    s3 = fmaf(rl_f32(p, (t0) + 3), kv.w, s3);

__global__ __launch_bounds__(64) void finalize_kernel(const float* __restrict__ emission,
                                                      const int* __restrict__ target,
                                                      const int* __restrict__ mask,
                                                      const float* __restrict__ trans,
                                                      const float* __restrict__ wsK,
                                                      float* __restrict__ out) {
    const int b = blockIdx.x;
    const int j = threadIdx.x;
    const int jj = j < 24 ? j : 23;
    const float* em = emission + (long)b * S_ * T_;
    const int* mk = mask + b * S_;

    float p = (j < 24) ? __expf(em[j]) : 0.f;   // p0
    float C = 0.f;

    for (int c = 0; c < NC_; ++c) {
        const float* base = wsK + (long)(b * NC_ + c) * KST_;
        C += base[1024];                        // chunk log-scale (uniform)
        const float4* rp = (const float4*)(base + jj * 32);
        const float4 k0 = rp[0], k1 = rp[1], k2 = rp[2], k3 = rp[3], k4 = rp[4], k5 = rp[5];
        float s0 = 0.f, s1 = 0.f, s2 = 0.f, s3 = 0.f;
        ACC4(k0, 0) ACC4(k1, 4) ACC4(k2, 8) ACC4(k3, 12) ACC4(k4, 16) ACC4(k5, 20)
        p = (j < 24) ? ((s0 + s1) + (s2 + s3)) : 0.f;
        // exact power-of-2 renorm by wave max
        float mx = p;
#pragma unroll
        for (int off = 32; off; off >>= 1) mx = fmaxf(mx, __shfl_xor(mx, off));
        const u32 ef = __float_as_uint(mx) & 0x7f800000u;
        p *= __uint_as_float(0x7f000000u - ef);
        C += (float)((int)(ef >> 23) - 127) * 0.6931471805599453f;
    }

    float ex = p;                               // lanes>=24 already 0
#pragma unroll
    for (int off = 32; off; off >>= 1) ex += __shfl_down(ex, off);

    // gold-path score (all 64 lanes)
    float ssum = 0.f;
#pragma unroll
    for (int kk = 0; kk < S_ / 64; ++kk) {
        const int s = j + kk * 64;
        if (mk[s]) {
            const int tg = target[b * S_ + s];
            float v = em[s * T_ + tg];
            if (s > 0) v += trans[target[b * S_ + s - 1] * T_ + tg];
            ssum += v;
        }
    }
#pragma unroll
    for (int off = 32; off; off >>= 1) ssum += __shfl_down(ssum, off);

    if (j == 0) {
        const float logZ = C + __logf(ex);
        atomicAdd(out, (logZ - ssum) * (1.0f / B_));
    }
}

extern "C" void kernel_launch(void* const* d_in, const int* in_sizes, int n_in,
                              void* d_out, int out_size, void* d_ws, size_t ws_size,
                              hipStream_t stream) {
    const float* feats  = (const float*)d_in[0];
    const int*   target = (const int*)d_in[1];
    const int*   mask   = (const int*)d_in[2];
    const float* W      = (const float*)d_in[3];
    const float* bias   = (const float*)d_in[4];
    const float* trans  = (const float*)d_in[5];

    float* out = (float*)d_out;
    float* emission = out + 1;            // output 1, written in place
    u16* Wh = (u16*)d_ws;                 // 32*1024 bf16 = 64 KB
    u16* Wl = Wh + TP_ * H_;              // 64 KB
    float* wsK = (float*)((char*)d_ws + 131072);  // 2048 * 1040 floats ~ 8.5 MB

    wcvt_kernel<<<(TP_ * H_) / 256, 256, 0, stream>>>(W, Wh, Wl, out);
    gemm_kernel<<<1024, 256, 0, stream>>>(feats, Wh, Wl, bias, emission);
    chunk_kernel<<<B_ * NC_, 64, 0, stream>>>(emission, mask, trans, wsK);
    finalize_kernel<<<B_, 64, 0, stream>>>(emission, target, mask, trans, wsK, out);
}